// Round 6
// baseline (244.829 us; speedup 1.0000x reference)
//
#include <hip/hip_runtime.h>
#include <stdint.h>

// DETR PartMap: [2, B, Q, H, W] outside-box masks (1.0 outside, 0.0 inside).
// B=64, Q=300, H=W=40. Output 61.44M fp32 = 245.8 MB -> pure write-BW problem.
//
// R6 = R5 with the compile fix: __builtin_nontemporal_store requires a native
// clang vector type, not HIP_vector_type<float,4>. Theory unchanged: limiter
// is L2 write-allocate/RFO (fillBuffer: 6.6 TB/s FETCH~0; my stores: 2.7 TB/s)
// -> nt store skips L2 allocation.

#define B_     64
#define Q_     300
#define HM     40
#define WM     40
#define NBOX   38400              // 2*B*Q
#define N4     15360000           // 2*B*Q*H*W / 4

typedef float f4_native __attribute__((ext_vector_type(4)));

__global__ __launch_bounds__(256) void box_prep_kernel(
    const float* __restrict__ obj,
    const float* __restrict__ sub,
    const int*   __restrict__ img,     // [B,2] = (h, w) int32
    uint32_t*    __restrict__ tbl)     // [NBOX][2]: {xmask_lo, xmask_hi|y1<<8|y2<<16}
{
    #pragma clang fp contract(off)
    int id = blockIdx.x * 256 + threadIdx.x;
    if (id >= NBOX) return;

    // id = (s*64 + b)*300 + q
    int q  = id % Q_;
    int sb = id / Q_;
    int b  = sb & 63;
    int s  = sb >> 6;

    const float* coord = s ? sub : obj;
    float4 c = ((const float4*)coord)[b * Q_ + q];   // (cx, cy, w, h)

    float shh = (float)img[b * 2 + 0];
    float sww = (float)img[b * 2 + 1];

    // Exact numpy op order: (cx - 0.5*w) * size / 32, floor, cast. No FMA.
    float x1f = (c.x - 0.5f * c.z) * sww / 32.0f;
    float y1f = (c.y - 0.5f * c.w) * shh / 32.0f;
    float x2f = (c.x + 0.5f * c.z) * sww / 32.0f;
    float y2f = (c.y + 0.5f * c.w) * shh / 32.0f;

    int x1 = (int)floorf(x1f);
    int y1 = (int)floorf(y1f);
    int x2 = min((int)floorf(x2f), WM - 1);
    int y2 = min((int)floorf(y2f), HM - 1);

    // 40-bit x-outside mask: bit x set iff (x < x1 || x > x2)
    uint64_t blo = (x1 <= 0) ? ~0ull : ~((1ull << x1) - 1ull);
    uint64_t bhi = (x2 < 0) ? 0ull : ((1ull << (x2 + 1)) - 1ull);
    uint64_t outside = (~(blo & bhi)) & ((1ull << 40) - 1ull);

    uint32_t d0 = (uint32_t)outside;
    uint32_t d1 = ((uint32_t)(outside >> 32) & 0xFFu)
                | (((uint32_t)y1 & 0xFFu) << 8)
                | (((uint32_t)y2 & 0xFFu) << 16);

    tbl[id * 2 + 0] = d0;
    tbl[id * 2 + 1] = d1;
}

__global__ __launch_bounds__(256) void partmap_stream_nt(
    const uint64_t* __restrict__ tbl,
    f4_native*      __restrict__ out)
{
    int idx = blockIdx.x * 256 + threadIdx.x;   // float4 index, < N4 exactly

    // idx = e*400 + h*10 + w4
    int e   = (int)((unsigned)idx / 400u);      // entry id (magic-mul)
    int rem = idx - e * 400;
    int h   = (int)((unsigned)rem / 10u);
    int w4  = rem - h * 10;
    int sh  = w4 * 4;

    uint64_t t = tbl[e];                        // L1 broadcast: 400 consecutive
                                                // threads share one entry
    int y1 = (int)(int8_t)(t >> 40);
    int y2 = (int)(int8_t)(t >> 48);

    // all-ones if row h outside [y1,y2]
    int rneg = ((h - y1) | (y2 - h)) >> 31;

    // bits sh..sh+3 of the 40-bit x-outside mask (sh<=36)
    uint32_t m = (uint32_t)(t >> sh) | (uint32_t)rneg;

    f4_native r;
    r.x = (float)( m        & 1u);
    r.y = (float)((m >> 1u) & 1u);
    r.z = (float)((m >> 2u) & 1u);
    r.w = (float)((m >> 3u) & 1u);

    __builtin_nontemporal_store(r, out + idx);  // nt: no L2 alloc / no RFO
}

extern "C" void kernel_launch(void* const* d_in, const int* in_sizes, int n_in,
                              void* d_out, int out_size, void* d_ws, size_t ws_size,
                              hipStream_t stream) {
    const float* obj = (const float*)d_in[0];   // [B,Q,4] f32
    const float* sub = (const float*)d_in[1];   // [B,Q,4] f32
    const int*   img = (const int*)d_in[2];     // [B,2] int32 (h, w)
    // d_in[3] = mask (bool) — only its shape is used; ignored.

    uint32_t*  tbl = (uint32_t*)d_ws;           // 38,400 * 8 B = 307 KB
    f4_native* out = (f4_native*)d_out;

    box_prep_kernel<<<dim3((NBOX + 255) / 256), dim3(256), 0, stream>>>(
        obj, sub, img, tbl);
    partmap_stream_nt<<<dim3(N4 / 256), dim3(256), 0, stream>>>(
        (const uint64_t*)tbl, out);
}

// Round 7
// 239.596 us; speedup vs baseline: 1.0218x; 1.0218x over previous
//
#include <hip/hip_runtime.h>
#include <stdint.h>

// DETR PartMap: [2, B, Q, H, W] outside-box masks (1.0 outside, 0.0 inside).
// B=64, Q=300, H=W=40. Output 61.44M fp32 = 245.8 MB -> pure write-BW problem.
//
// R7: single fused PERSISTENT kernel. Model refit over R1-R6: timed window =
// harness poison fills (~186 us fixed) + kernel (~50-57 us for all lean
// variants vs ~37 us pure-store floor). This round removes the remaining
// structural overheads at once: no box_prep kernel, no d_ws table, no second
// launch, no readlanes, no multi-round tail. 8192 waves (2048 blk x 256 = 32
// waves/CU, one residency); wave w walks entries [75w/16, 75(w+1)/16) (4-5
// contiguous boxes). Entry is wave-uniform: every lane computes the box from
// a broadcast 16B coord load. Inner loop per entry: 7 predicated dwordx4
// stores with ~16 VALU insts each (row-sign + 64-bit shift + 4x bit->float).

#define B_   64
#define Q_   300
#define HM   40
#define WM   40
#define NBOX 38400                // 2*B*Q

typedef float f4_native __attribute__((ext_vector_type(4)));

__global__ __launch_bounds__(256) void partmap_persist(
    const float* __restrict__ obj,
    const float* __restrict__ sub,
    const int*   __restrict__ img,     // [B,2] = (h, w) int32
    f4_native*   __restrict__ out)     // [2,B,Q,H,W] as 400 f4 per entry
{
    #pragma clang fp contract(off)
    const int lane = threadIdx.x & 63;
    const int w    = (blockIdx.x << 2) | (threadIdx.x >> 6);   // wave id 0..8191

    // contiguous entry range for this wave: 38400/8192 = 75/16 per wave
    const int e0 = (w * 75) >> 4;
    const int e1 = ((w + 1) * 75) >> 4;       // e1-e0 in {4,5}

    // per-lane row/shift tables, computed once, reused for every entry.
    // iteration j covers float4 positions p = j*64 + lane (p<400 valid).
    int h_j[7], sh_j[7];
    #pragma unroll
    for (int j = 0; j < 7; ++j) {
        int p  = j * 64 + lane;
        int h  = (int)((unsigned)p / 10u);
        int w4 = p - 10 * h;
        h_j[j]  = h;
        sh_j[j] = w4 * 4;
    }

    for (int e = e0; e < e1; ++e) {
        // ---- wave-uniform box compute (all lanes same values, broadcast loads)
        int q  = e % Q_;                       // e = (s*64 + b)*300 + q
        int sb = e / Q_;
        int b  = sb & 63;
        int s  = sb >> 6;

        const float* coord = s ? sub : obj;
        float4 c = ((const float4*)coord)[b * Q_ + q];   // (cx, cy, w, h)

        float shh = (float)img[b * 2 + 0];
        float sww = (float)img[b * 2 + 1];

        // Exact numpy op order: (cx - 0.5*w) * size / 32, floor, cast. No FMA.
        float x1f = (c.x - 0.5f * c.z) * sww / 32.0f;
        float y1f = (c.y - 0.5f * c.w) * shh / 32.0f;
        float x2f = (c.x + 0.5f * c.z) * sww / 32.0f;
        float y2f = (c.y + 0.5f * c.w) * shh / 32.0f;

        int x1 = (int)floorf(x1f);                  // in (-20, 40)
        int y1 = (int)floorf(y1f);
        int x2 = min((int)floorf(x2f), WM - 1);     // in [0, 39]
        int y2 = min((int)floorf(y2f), HM - 1);

        // 40-bit x-outside mask: bit x set iff (x < x1 || x > x2)
        uint64_t blo = (x1 <= 0) ? ~0ull : ~((1ull << x1) - 1ull);
        uint64_t bhi = (1ull << (x2 + 1)) - 1ull;
        uint64_t outside = (~(blo & bhi)) & ((1ull << 40) - 1ull);

        // ---- stream this entry: 7 coalesced dwordx4 stores per lane
        f4_native* ep = out + (size_t)e * 400 + lane;

        #pragma unroll
        for (int j = 0; j < 7; ++j) {
            // all-ones if row h outside [y1,y2]
            int rneg = ((h_j[j] - y1) | (y2 - h_j[j])) >> 31;
            uint32_t m = (uint32_t)(outside >> sh_j[j]) | (uint32_t)rneg;

            f4_native r;
            r.x = (float)( m        & 1u);
            r.y = (float)((m >> 1u) & 1u);
            r.z = (float)((m >> 2u) & 1u);
            r.w = (float)((m >> 3u) & 1u);

            if (j < 6 || lane < 16)          // entry has 400 f4 (= 6*64 + 16)
                ep[j * 64] = r;
        }
    }
}

extern "C" void kernel_launch(void* const* d_in, const int* in_sizes, int n_in,
                              void* d_out, int out_size, void* d_ws, size_t ws_size,
                              hipStream_t stream) {
    const float* obj = (const float*)d_in[0];   // [B,Q,4] f32
    const float* sub = (const float*)d_in[1];   // [B,Q,4] f32
    const int*   img = (const int*)d_in[2];     // [B,2] int32 (h, w)
    // d_in[3] = mask (bool) — only its shape is used; ignored.

    f4_native* out = (f4_native*)d_out;         // [2,B,Q,H,W] f32

    partmap_persist<<<dim3(2048), dim3(256), 0, stream>>>(obj, sub, img, out);
}